// Round 12
// baseline (194.186 us; speedup 1.0000x reference)
//
#include <hip/hip_runtime.h>
#include <float.h>

#define B_ 16
#define D_ 64
#define L_ 8192
#define K_ 512
#define NBLOCKS 1024
#define TILES_PER_BLOCK 2
#define EPS 0.0625f           // fp16 score err 6sigma*2 ~= 0.039 < EPS; exact pass covers flags

// r12: occupancy redesign. r11 null result -> VGPR HW quantum {64,128,256}
// (m68/m69): VGPR 84 rounds to 128 -> 16 waves/CU cap, grid irrelevant.
// Only path to 32 waves/CU: VGPR <= 64. 1024-thr blocks, 16 waves x 32 codes
// -> Bh 16 regs (was 32), acc 8 (was 16); launch_bounds(1024,2) pins cap 64.
// All validated numerics (esq/xsq/exact np chains, xAh frag byte layout) kept.

typedef __attribute__((ext_vector_type(8))) _Float16 half8;
typedef __attribute__((ext_vector_type(4))) _Float16 half4;
typedef __attribute__((ext_vector_type(4))) float    f32x4;

__device__ __forceinline__ unsigned f32_sortable(float x) {
    unsigned u = __float_as_uint(x);
    return u ^ (((int)u >> 31) | 0x80000000u);   // ascending uint == ascending float
}

__global__ __launch_bounds__(1024, 2)
void vq_mfma_kernel(const float* __restrict__ X, const float* __restrict__ E,
                    float* __restrict__ out_emb, float* __restrict__ out_idx)
{
    __shared__ __align__(16) short xAh[4096];    // fp16 A-frags, validated layout, 8 KB
    __shared__ float xT[64][68];                 // fp32 x, [d][token]; pad 68: <=2-way banks
    __shared__ float esq_s[K_];
    __shared__ float xsq_s[64];
    __shared__ float redm1[16][68];
    __shared__ float redm2[16][68];
    __shared__ int   redk1[16][68];
    __shared__ int bestk_s[64];
    __shared__ int flag_s[64];
    __shared__ int nflag_s;

    const int tid  = threadIdx.x;
    const int lane = tid & 63;
    const int wave = tid >> 6;        // 0..15
    const int lo4  = lane & 15;
    const int hi4  = lane >> 4;

    // ---- esq: np sequential axis-0 (round square, ordered adds) — bit-exact r9 chain
    if (tid < 512) {
        float s = 0.f;
        #pragma unroll
        for (int c = 0; c < 4; ++c) {
            float v[16];
            #pragma unroll
            for (int m = 0; m < 16; ++m) v[m] = E[(c * 16 + m) * K_ + tid];
            #pragma unroll
            for (int m = 0; m < 16; ++m) {
                float sq = v[m] * v[m];
                asm volatile("" : "+v"(sq));     // np rounds the square first
                s = s + sq;
            }
        }
        esq_s[tid] = s;
    }

    // ---- resident fp16 B-frags: 16 regs. Wave w owns codes w*32..w*32+31 ----
    half8 Bh[2][2];
    #pragma unroll
    for (int q = 0; q < 2; ++q) {
        int code = (wave * 2 + q) * 16 + lo4;
        #pragma unroll
        for (int s = 0; s < 2; ++s) {
            half8 h;
            #pragma unroll
            for (int j = 0; j < 8; ++j) {
                int d = s * 32 + hi4 * 8 + j;
                h[j] = (_Float16)E[d * K_ + code];   // v_cvt_f16_f32, RNE
            }
            Bh[q][s] = h;
        }
    }

    for (int t = 0; t < TILES_PER_BLOCK; ++t) {
        int tile = blockIdx.x * TILES_PER_BLOCK + t;
        int b  = tile >> 7;
        int l0 = (tile & 127) << 6;

        __syncthreads();                                         // B1

        // ---- stage x: wave w loads d-rows w*4..w*4+3, token = lane ----
        // xAh unit (tb*2+s)*64 + g*16 + row holds fp16 X[d=s*32+g*8+j][tok=tb*16+row];
        // wave w = 8u'+... : u=w>>1 selects (s=u>>2, g=u&3), h=w&1 selects j-half.
        {
            const float* xb = X + ((size_t)(b * 64 + wave * 4)) * L_ + l0 + lane;
            float xv[4];
            #pragma unroll
            for (int r = 0; r < 4; ++r) xv[r] = xb[(size_t)r * L_];
            #pragma unroll
            for (int r = 0; r < 4; ++r) xT[wave * 4 + r][lane] = xv[r];
            half4 h4;
            #pragma unroll
            for (int r = 0; r < 4; ++r) h4[r] = (_Float16)xv[r];
            int u = wave >> 1, h = wave & 1;
            int tb = lane >> 4, row = lane & 15;
            int unit = (tb * 2 + (u >> 2)) * 64 + (u & 3) * 16 + row;
            ((half4*)xAh)[unit * 2 + h] = h4;
        }
        if (tid == 0) nflag_s = 0;
        __syncthreads();                                         // B2

        // ---- xsq: np pairwise-8, bit-exact r9 chain (8 lanes/token) ----
        if (tid < 512) {
            int tk = tid >> 3;
            int j  = tid & 7;
            float r = 0.f;
            #pragma unroll
            for (int m = 0; m < 8; ++m) {
                float v = xT[m * 8 + j][tk];
                float sq = v * v;
                asm volatile("" : "+v"(sq));     // np rounds the square first
                r = r + sq;                      // m ascending: np r[j] order
            }
            r = r + __shfl_xor(r, 1, 64);
            r = r + __shfl_xor(r, 2, 64);
            r = r + __shfl_xor(r, 4, 64);        // np pairwise combine tree
            if (j == 0) xsq_s[tk] = r;
        }
        __syncthreads();                                         // B3

        float es_q0 = esq_s[(wave * 2 + 0) * 16 + lo4];
        float es_q1 = esq_s[(wave * 2 + 1) * 16 + lo4];
        const int cd0 = (wave * 2 + 0) * 16 + lo4;
        const int cd1 = cd0 + 16;

        // ---- per row-block: 4 MFMA -> scores -> (m1,k1,m2) -> 4-stage tree
        #pragma unroll
        for (int tb = 0; tb < 4; ++tb) {
            half8 ah0 = ((const half8*)xAh)[(tb * 2 + 0) * 64 + lane];
            half8 ah1 = ((const half8*)xAh)[(tb * 2 + 1) * 64 + lane];
            f32x4 c0 = {0.f, 0.f, 0.f, 0.f};
            c0 = __builtin_amdgcn_mfma_f32_16x16x32_f16(ah0, Bh[0][0], c0, 0, 0, 0);
            c0 = __builtin_amdgcn_mfma_f32_16x16x32_f16(ah1, Bh[0][1], c0, 0, 0, 0);
            f32x4 c1 = {0.f, 0.f, 0.f, 0.f};
            c1 = __builtin_amdgcn_mfma_f32_16x16x32_f16(ah0, Bh[1][0], c1, 0, 0, 0);
            c1 = __builtin_amdgcn_mfma_f32_16x16x32_f16(ah1, Bh[1][1], c1, 0, 0, 0);

            float m1[4], m2[4];
            int   k1[4];
            #pragma unroll
            for (int r = 0; r < 4; ++r) {
                float xs = xsq_s[tb * 16 + hi4 * 4 + r];
                float s0 = (xs - 2.0f * c0[r]) + es_q0;
                float s1 = (xs - 2.0f * c1[r]) + es_q1;
                if (s0 <= s1) { m1[r] = s0; k1[r] = cd0; m2[r] = s1; }
                else          { m1[r] = s1; k1[r] = cd1; m2[r] = s0; }
            }
            #pragma unroll
            for (int off = 1; off < 16; off <<= 1)
                #pragma unroll
                for (int r = 0; r < 4; ++r) {
                    float ov = __shfl_xor(m1[r], off, 64);
                    int   ok = __shfl_xor(k1[r], off, 64);
                    float o2 = __shfl_xor(m2[r], off, 64);
                    float n2 = fminf(fminf(m2[r], o2), fmaxf(m1[r], ov));
                    if (ov < m1[r] || (ov == m1[r] && ok < k1[r])) {
                        m1[r] = ov; k1[r] = ok;
                    }
                    m2[r] = n2;
                }
            if (lo4 == 0)
                #pragma unroll
                for (int r = 0; r < 4; ++r) {
                    int token = tb * 16 + hi4 * 4 + r;
                    redm1[wave][token] = m1[r];
                    redk1[wave][token] = k1[r];
                    redm2[wave][token] = m2[r];
                }
        }
        __syncthreads();                                         // B4

        // ---- combine 16 slots: thread = (token, slot), shfl over slot bits
        {
            int tk   = tid >> 4;       // 0..63
            int slot = tid & 15;
            float a    = redm1[slot][tk];
            float bsec = redm2[slot][tk];
            int   ka   = redk1[slot][tk];
            #pragma unroll
            for (int off = 1; off < 16; off <<= 1) {
                float ov = __shfl_xor(a, off, 64);
                int   ok = __shfl_xor(ka, off, 64);
                float o2 = __shfl_xor(bsec, off, 64);
                float n2 = fminf(fminf(bsec, o2), fmaxf(a, ov));
                if (ov < a || (ov == a && ok < ka)) { a = ov; ka = ok; }
                bsec = n2;
            }
            if (slot == 0) {
                if (bsec <= a + EPS) {           // near-tie -> exact recompute
                    int p = atomicAdd(&nflag_s, 1);
                    flag_s[p] = tk;
                } else {
                    bestk_s[tk] = ka;            // unique winner == np argmin
                }
            }
        }
        __syncthreads();                                         // B5

        // ---- exact pass: wave-parallel, no inner barriers; np-bitexact chain
        {
            int nf = nflag_s;
            for (int f = wave; f < nf; f += 16) {
                int token = flag_s[f];
                float xs = xsq_s[token];
                float d0 = 0.f, d1 = 0.f, d2 = 0.f, d3 = 0.f;
                float d4 = 0.f, d5 = 0.f, d6 = 0.f, d7 = 0.f;
                const float* Ep = E + 8 * lane;
                #pragma unroll 4
                for (int d = 0; d < 64; ++d) {
                    float xv = xT[d][token];     // wave-uniform broadcast
                    float4 e0 = *reinterpret_cast<const float4*>(Ep + d * K_);
                    float4 e1 = *reinterpret_cast<const float4*>(Ep + d * K_ + 4);
                    d0 = fmaf(xv, e0.x, d0); d1 = fmaf(xv, e0.y, d1);
                    d2 = fmaf(xv, e0.z, d2); d3 = fmaf(xv, e0.w, d3);
                    d4 = fmaf(xv, e1.x, d4); d5 = fmaf(xv, e1.y, d5);
                    d6 = fmaf(xv, e1.z, d6); d7 = fmaf(xv, e1.w, d7);
                }
                float4 qa = *reinterpret_cast<const float4*>(&esq_s[8 * lane]);
                float4 qb = *reinterpret_cast<const float4*>(&esq_s[8 * lane + 4]);
                float sc[8];
                sc[0] = (xs - 2.0f * d0) + qa.x; sc[1] = (xs - 2.0f * d1) + qa.y;
                sc[2] = (xs - 2.0f * d2) + qa.z; sc[3] = (xs - 2.0f * d3) + qa.w;
                sc[4] = (xs - 2.0f * d4) + qb.x; sc[5] = (xs - 2.0f * d5) + qb.y;
                sc[6] = (xs - 2.0f * d6) + qb.z; sc[7] = (xs - 2.0f * d7) + qb.w;
                unsigned long long pk = ~0ULL;
                #pragma unroll
                for (int j = 0; j < 8; ++j) {    // ascending code: first-min kept
                    unsigned long long p =
                        ((unsigned long long)f32_sortable(sc[j]) << 32) |
                        (unsigned)(8 * lane + j);
                    if (p < pk) pk = p;
                }
                #pragma unroll
                for (int off = 1; off < 64; off <<= 1) {
                    unsigned long long o = __shfl_xor(pk, off, 64);
                    if (o < pk) pk = o;
                }
                if (lane == 0)
                    bestk_s[token] = (int)(unsigned)(pk & 0xFFFFFFFFULL);
            }
        }
        __syncthreads();                                         // B6

        // ---- epilogue: thread = (d, token-quad); one float4 gather+store ---
        {
            int qd = tid & 15, d = tid >> 4;     // d 0..63
            int i4 = qd * 4;
            int k0 = bestk_s[i4],     kk1 = bestk_s[i4 + 1];
            int k2 = bestk_s[i4 + 2], k3  = bestk_s[i4 + 3];
            float4 v;
            v.x = E[d * K_ + k0];  v.y = E[d * K_ + kk1];
            v.z = E[d * K_ + k2];  v.w = E[d * K_ + k3];
            *reinterpret_cast<float4*>(out_emb + ((size_t)(b * 64 + d)) * L_ + l0 + i4) = v;
        }
        if (tid < 64)
            out_idx[(size_t)b * L_ + l0 + tid] = (float)bestk_s[tid];
    }
}

extern "C" void kernel_launch(void* const* d_in, const int* in_sizes, int n_in,
                              void* d_out, int out_size, void* d_ws, size_t ws_size,
                              hipStream_t stream) {
    const float* X = (const float*)d_in[0];   // (B, D, L) fp32
    const float* E = (const float*)d_in[1];   // (D, K) fp32
    float* out     = (float*)d_out;
    float* out_emb = out;
    float* out_idx = out + (size_t)B_ * D_ * L_;
    vq_mfma_kernel<<<NBLOCKS, 1024, 0, stream>>>(X, E, out_emb, out_idx);
}

// Round 13
// 66.306 us; speedup vs baseline: 2.9286x; 2.9286x over previous
//
#include <hip/hip_runtime.h>
#include <float.h>

#define B_ 16
#define D_ 64
#define L_ 8192
#define K_ 512
#define NBLOCKS 256
#define TILE_TOK 128
#define TILES_PER_BLOCK 4     // 1024 tiles / 256 blocks, 1 block/CU
#define EPS 0.0625f           // fp16 score err bound << EPS; exact pass covers flags

// r13: swapped-operand MFMA (codes=A-rows, tokens=B-cols) -> lane owns ONE
// token's scores across all 512 codes. Argmin = register fold + 2 shfl merges.
// Deletes per-tb shfl trees, red-LDS, B4/B5 (r12 lesson: critical path, not
// occupancy, is the binding constraint). 3 barriers/tile. E-frags in LDS
// (64 KB, reused x4 tiles); token B-frags resident (8 VGPRs).

typedef __attribute__((ext_vector_type(8))) _Float16 half8;
typedef __attribute__((ext_vector_type(4))) float    f32x4;

__device__ __forceinline__ unsigned f32_sortable(float x) {
    unsigned u = __float_as_uint(x);
    return u ^ (((int)u >> 31) | 0x80000000u);   // ascending uint == ascending float
}

__global__ __launch_bounds__(512, 1)
void vq_mfma_kernel(const float* __restrict__ X, const float* __restrict__ E,
                    float* __restrict__ out_emb, float* __restrict__ out_idx)
{
    __shared__ __align__(16) short eF[32768];    // E fp16 A-frags: [blk][kh][fl] x8, 64 KB
    __shared__ __align__(16) short xAh[8192];    // X fp16 B-frags: [tb][kh][fl] x8, 16 KB
    __shared__ float xT[64][132];                // fp32 x, [d][token], 33.8 KB
    __shared__ float esq_s[K_];
    __shared__ int   bestk_s[TILE_TOK];

    const int tid  = threadIdx.x;
    const int lane = tid & 63;
    const int wave = tid >> 6;        // 0..7
    const int lo4  = lane & 15;
    const int hi4  = lane >> 4;

    // ---- esq: np sequential axis-0 (round square, ordered adds) — r9 verbatim
    {
        float s = 0.f;
        #pragma unroll
        for (int c = 0; c < 4; ++c) {
            float v[16];
            #pragma unroll
            for (int m = 0; m < 16; ++m) v[m] = E[(c * 16 + m) * K_ + tid];
            #pragma unroll
            for (int m = 0; m < 16; ++m) {
                float sq = v[m] * v[m];
                asm volatile("" : "+v"(sq));     // np rounds the square first
                s = s + sq;
            }
        }
        esq_s[tid] = s;
    }

    // ---- E fp16 A-frags into LDS (once; reused all tiles) ----
    // unit (blk,kh), frag-lane fl holds E[d = kh*32+(fl>>4)*8+j][code = blk*16+(fl&15)]
    {
        int fl = tid & 63, pr = tid >> 6;        // pr 0..7
        #pragma unroll
        for (int it = 0; it < 8; ++it) {
            int idx = it * 8 + pr;               // 0..63 = (blk, kh)
            int blk = idx >> 1, kh = idx & 1;
            half8 h;
            #pragma unroll
            for (int j = 0; j < 8; ++j)
                h[j] = (_Float16)E[(kh * 32 + (fl >> 4) * 8 + j) * K_ + blk * 16 + (fl & 15)];
            ((half8*)eF)[(blk * 2 + kh) * 64 + fl] = h;
        }
    }

    for (int t = 0; t < TILES_PER_BLOCK; ++t) {
        int tile = blockIdx.x * TILES_PER_BLOCK + t;
        int b  = tile >> 6;                      // tile / 64
        int l0 = (tile & 63) << 7;               // (tile % 64) * 128

        __syncthreads();                                         // B1

        // ---- stage X: thread = (d-group wave*8.., 2 token-halves) ----
        {
            const float* xb = X + ((size_t)(b * 64 + wave * 8)) * L_ + l0 + lane;
            #pragma unroll
            for (int hh = 0; hh < 2; ++hh) {
                int tok = hh * 64 + lane;
                float xv[8];
                #pragma unroll
                for (int r = 0; r < 8; ++r) xv[r] = xb[(size_t)r * L_ + hh * 64];
                #pragma unroll
                for (int r = 0; r < 8; ++r) xT[wave * 8 + r][tok] = xv[r];
                half8 h8;
                #pragma unroll
                for (int r = 0; r < 8; ++r) h8[r] = (_Float16)xv[r];   // d = wave*8+r, j=r
                int tb = tok >> 4, kh = wave >> 2;
                int fl = (wave & 3) * 16 + (tok & 15);
                ((half8*)xAh)[(tb * 2 + kh) * 64 + fl] = h8;
            }
        }
        __syncthreads();                                         // B2

        // ---- xsq: wave-local np pairwise-8; lane's token = wave*16 + (lane&15)
        float xs;
        {
            int token = wave * 16 + lo4;
            int ja = 2 * hi4, jb = ja + 1;
            float ra = 0.f, rb = 0.f;
            #pragma unroll
            for (int m = 0; m < 8; ++m) {
                float va = xT[m * 8 + ja][token];
                float vb = xT[m * 8 + jb][token];
                float sa = va * va, sb = vb * vb;
                asm volatile("" : "+v"(sa));     // np rounds squares first
                asm volatile("" : "+v"(sb));
                ra = ra + sa;                    // m ascending: np r8[j] order
                rb = rb + sb;
            }
            float s = ra + rb;                   // (r[2h] + r[2h+1])
            s = s + __shfl_xor(s, 16, 64);       // h=0: (r0+r1)+(r2+r3)
            s = s + __shfl_xor(s, 32, 64);       // h=0: full np pairwise tree
            xs = __shfl(s, lo4, 64);             // broadcast h=0 lane's value
        }

        // ---- token B-frags resident (8 regs) ----
        half8 bh0 = ((const half8*)xAh)[(wave * 2 + 0) * 64 + lane];
        half8 bh1 = ((const half8*)xAh)[(wave * 2 + 1) * 64 + lane];

        // ---- main: 32 code-blocks, register-local triple fold, no barriers
        float m1 = FLT_MAX, m2 = FLT_MAX;
        int   k1 = 0x7FFFFFFF;
        #pragma unroll 8
        for (int blk = 0; blk < 32; ++blk) {
            half8 ah0 = ((const half8*)eF)[(blk * 2 + 0) * 64 + lane];
            half8 ah1 = ((const half8*)eF)[(blk * 2 + 1) * 64 + lane];
            f32x4 c = {0.f, 0.f, 0.f, 0.f};
            c = __builtin_amdgcn_mfma_f32_16x16x32_f16(ah0, bh0, c, 0, 0, 0);
            c = __builtin_amdgcn_mfma_f32_16x16x32_f16(ah1, bh1, c, 0, 0, 0);
            float4 es4 = *reinterpret_cast<const float4*>(&esq_s[blk * 16 + hi4 * 4]);
            float es[4] = {es4.x, es4.y, es4.z, es4.w};
            #pragma unroll
            for (int r = 0; r < 4; ++r) {
                float sc = (xs - 2.0f * c[r]) + es[r];
                int   cd = blk * 16 + hi4 * 4 + r;     // ascending within lane
                if (sc < m1)      { m2 = m1; m1 = sc; k1 = cd; }
                else              { m2 = fminf(m2, sc); }
            }
        }

        // ---- merge 4 lanes per token (xor 16, 32) — r9-validated logic ----
        #pragma unroll
        for (int off = 16; off < 64; off <<= 1) {
            float ov = __shfl_xor(m1, off, 64);
            int   ok = __shfl_xor(k1, off, 64);
            float o2 = __shfl_xor(m2, off, 64);
            float n2 = fminf(fminf(m2, o2), fmaxf(m1, ov));
            if (ov < m1 || (ov == m1 && ok < k1)) { m1 = ov; k1 = ok; }
            m2 = n2;
        }

        // ---- decide / flag (lanes 0..15 own tokens wave*16+lane) ----
        bool mine = (lane < 16);
        bool flg  = mine && (m2 <= m1 + EPS);
        if (mine && !flg) bestk_s[wave * 16 + lane] = k1;
        unsigned long long bal = __ballot(flg);

        // ---- exact pass: wave-local, per flagged token; np-bitexact chain --
        while (bal) {
            int tk_local = (int)__builtin_ctzll(bal);
            bal &= bal - 1;
            int token = wave * 16 + tk_local;
            float xs_e = __shfl(xs, tk_local, 64);
            float d0 = 0.f, d1 = 0.f, d2 = 0.f, d3 = 0.f;
            float d4 = 0.f, d5 = 0.f, d6 = 0.f, d7 = 0.f;
            const float* Ep = E + 8 * lane;
            #pragma unroll 4
            for (int d = 0; d < 64; ++d) {
                float xv = xT[d][token];         // wave-uniform broadcast
                float4 e0 = *reinterpret_cast<const float4*>(Ep + d * K_);
                float4 e1 = *reinterpret_cast<const float4*>(Ep + d * K_ + 4);
                d0 = fmaf(xv, e0.x, d0); d1 = fmaf(xv, e0.y, d1);
                d2 = fmaf(xv, e0.z, d2); d3 = fmaf(xv, e0.w, d3);
                d4 = fmaf(xv, e1.x, d4); d5 = fmaf(xv, e1.y, d5);
                d6 = fmaf(xv, e1.z, d6); d7 = fmaf(xv, e1.w, d7);
            }
            float4 qa = *reinterpret_cast<const float4*>(&esq_s[8 * lane]);
            float4 qb = *reinterpret_cast<const float4*>(&esq_s[8 * lane + 4]);
            float sc[8];
            sc[0] = (xs_e - 2.0f * d0) + qa.x; sc[1] = (xs_e - 2.0f * d1) + qa.y;
            sc[2] = (xs_e - 2.0f * d2) + qa.z; sc[3] = (xs_e - 2.0f * d3) + qa.w;
            sc[4] = (xs_e - 2.0f * d4) + qb.x; sc[5] = (xs_e - 2.0f * d5) + qb.y;
            sc[6] = (xs_e - 2.0f * d6) + qb.z; sc[7] = (xs_e - 2.0f * d7) + qb.w;
            unsigned long long pk = ~0ULL;
            #pragma unroll
            for (int j = 0; j < 8; ++j) {        // ascending code: first-min kept
                unsigned long long p =
                    ((unsigned long long)f32_sortable(sc[j]) << 32) |
                    (unsigned)(8 * lane + j);
                if (p < pk) pk = p;
            }
            #pragma unroll
            for (int off = 1; off < 64; off <<= 1) {
                unsigned long long o = __shfl_xor(pk, off, 64);
                if (o < pk) pk = o;
            }
            if (lane == 0)
                bestk_s[token] = (int)(unsigned)(pk & 0xFFFFFFFFULL);
        }
        __syncthreads();                                         // B3

        // ---- epilogue: gather exact fp32 rows, float4 stores, 128 tokens --
        {
            int d  = tid >> 3;                   // 0..63
            int q8 = tid & 7;
            #pragma unroll
            for (int it = 0; it < 4; ++it) {
                int quad = q8 + it * 8;          // 0..31
                int i4 = quad * 4;
                int k0 = bestk_s[i4],     kk1 = bestk_s[i4 + 1];
                int k2 = bestk_s[i4 + 2], k3  = bestk_s[i4 + 3];
                float4 v;
                v.x = E[d * K_ + k0];  v.y = E[d * K_ + kk1];
                v.z = E[d * K_ + k2];  v.w = E[d * K_ + k3];
                *reinterpret_cast<float4*>(out_emb + ((size_t)(b * 64 + d)) * L_ + l0 + i4) = v;
            }
        }
        if (tid < TILE_TOK)
            out_idx[(size_t)b * L_ + l0 + tid] = (float)bestk_s[tid];
    }
}

extern "C" void kernel_launch(void* const* d_in, const int* in_sizes, int n_in,
                              void* d_out, int out_size, void* d_ws, size_t ws_size,
                              hipStream_t stream) {
    const float* X = (const float*)d_in[0];   // (B, D, L) fp32
    const float* E = (const float*)d_in[1];   // (D, K) fp32
    float* out     = (float*)d_out;
    float* out_emb = out;
    float* out_idx = out + (size_t)B_ * D_ * L_;
    vq_mfma_kernel<<<NBLOCKS, 512, 0, stream>>>(X, E, out_emb, out_idx);
}

// Round 14
// 65.058 us; speedup vs baseline: 2.9848x; 1.0192x over previous
//
#include <hip/hip_runtime.h>
#include <float.h>

#define B_ 16
#define D_ 64
#define L_ 8192
#define K_ 512
#define NBLOCKS 256
#define TILE_TOK 128
#define TILES_PER_BLOCK 4     // 1024 tiles / 256 blocks, 1 block/CU
#define EPS 0.0625f           // approx-score err (fp16 dot + reassoc) << EPS/2

// r14 = r13 + (a) T14 register prefetch of next tile's X (issue-early,
// write-late: HBM latency hides under ~30K-cycle compute), (b) xs dropped
// from approx fold (constant per token -> gap unchanged; exact pass keeps
// the full np chain). r13 matched prediction: 132 -> 66 us.

typedef __attribute__((ext_vector_type(8))) _Float16 half8;
typedef __attribute__((ext_vector_type(4))) float    f32x4;

__device__ __forceinline__ unsigned f32_sortable(float x) {
    unsigned u = __float_as_uint(x);
    return u ^ (((int)u >> 31) | 0x80000000u);   // ascending uint == ascending float
}

__global__ __launch_bounds__(512, 1)
void vq_mfma_kernel(const float* __restrict__ X, const float* __restrict__ E,
                    float* __restrict__ out_emb, float* __restrict__ out_idx)
{
    __shared__ __align__(16) short eF[32768];    // E fp16 A-frags: [blk][kh][fl] x8, 64 KB
    __shared__ __align__(16) short xAh[8192];    // X fp16 B-frags: [tb][kh][fl] x8, 16 KB
    __shared__ float xT[64][132];                // fp32 x, [d][token], 33.8 KB
    __shared__ float esq_s[K_];
    __shared__ int   bestk_s[TILE_TOK];

    const int tid  = threadIdx.x;
    const int lane = tid & 63;
    const int wave = tid >> 6;        // 0..7
    const int lo4  = lane & 15;
    const int hi4  = lane >> 4;

    // ---- esq: np sequential axis-0 (round square, ordered adds) — r9 verbatim
    {
        float s = 0.f;
        #pragma unroll
        for (int c = 0; c < 4; ++c) {
            float v[16];
            #pragma unroll
            for (int m = 0; m < 16; ++m) v[m] = E[(c * 16 + m) * K_ + tid];
            #pragma unroll
            for (int m = 0; m < 16; ++m) {
                float sq = v[m] * v[m];
                asm volatile("" : "+v"(sq));     // np rounds the square first
                s = s + sq;
            }
        }
        esq_s[tid] = s;
    }

    // ---- E fp16 A-frags into LDS (once; reused all tiles) ----
    // unit (blk,kh), frag-lane fl holds E[d = kh*32+(fl>>4)*8+j][code = blk*16+(fl&15)]
    {
        int fl = tid & 63, pr = tid >> 6;        // pr 0..7
        #pragma unroll
        for (int it = 0; it < 8; ++it) {
            int idx = it * 8 + pr;               // 0..63 = (blk, kh)
            int blk = idx >> 1, kh = idx & 1;
            half8 h;
            #pragma unroll
            for (int j = 0; j < 8; ++j)
                h[j] = (_Float16)E[(kh * 32 + (fl >> 4) * 8 + j) * K_ + blk * 16 + (fl & 15)];
            ((half8*)eF)[(blk * 2 + kh) * 64 + fl] = h;
        }
    }

    // ---- T14 prefetch: tile 0's X into registers ----
    float pf[2][8];
    {
        int tile = blockIdx.x * TILES_PER_BLOCK;
        int b  = tile >> 6;
        int l0 = (tile & 63) << 7;
        const float* xb = X + ((size_t)(b * 64 + wave * 8)) * L_ + l0 + lane;
        #pragma unroll
        for (int hh = 0; hh < 2; ++hh)
            #pragma unroll
            for (int r = 0; r < 8; ++r)
                pf[hh][r] = xb[(size_t)r * L_ + hh * 64];
    }

    for (int t = 0; t < TILES_PER_BLOCK; ++t) {
        int tile = blockIdx.x * TILES_PER_BLOCK + t;
        int b  = tile >> 6;                      // tile / 64
        int l0 = (tile & 63) << 7;               // (tile % 64) * 128

        __syncthreads();                                         // B1

        // ---- STAGE_WRITE from prefetch regs (write-late) ----
        #pragma unroll
        for (int hh = 0; hh < 2; ++hh) {
            int tok = hh * 64 + lane;
            #pragma unroll
            for (int r = 0; r < 8; ++r) xT[wave * 8 + r][tok] = pf[hh][r];
            half8 h8;
            #pragma unroll
            for (int r = 0; r < 8; ++r) h8[r] = (_Float16)pf[hh][r];  // d=wave*8+r
            int tb = tok >> 4, kh = wave >> 2;
            int fl = (wave & 3) * 16 + (tok & 15);
            ((half8*)xAh)[(tb * 2 + kh) * 64 + fl] = h8;
        }

        // ---- issue next tile's loads NOW (latency hides under compute) ----
        if (t < TILES_PER_BLOCK - 1) {
            int nt = tile + 1;
            int nb  = nt >> 6;
            int nl0 = (nt & 63) << 7;
            const float* xb = X + ((size_t)(nb * 64 + wave * 8)) * L_ + nl0 + lane;
            #pragma unroll
            for (int hh = 0; hh < 2; ++hh)
                #pragma unroll
                for (int r = 0; r < 8; ++r)
                    pf[hh][r] = xb[(size_t)r * L_ + hh * 64];
        }
        __syncthreads();                                         // B2

        // ---- xsq: wave-local np pairwise-8; lane's token = wave*16 + (lane&15)
        float xs;
        {
            int token = wave * 16 + lo4;
            int ja = 2 * hi4, jb = ja + 1;
            float ra = 0.f, rb = 0.f;
            #pragma unroll
            for (int m = 0; m < 8; ++m) {
                float va = xT[m * 8 + ja][token];
                float vb = xT[m * 8 + jb][token];
                float sa = va * va, sb = vb * vb;
                asm volatile("" : "+v"(sa));     // np rounds squares first
                asm volatile("" : "+v"(sb));
                ra = ra + sa;                    // m ascending: np r8[j] order
                rb = rb + sb;
            }
            float s = ra + rb;                   // (r[2h] + r[2h+1])
            s = s + __shfl_xor(s, 16, 64);       // h=0: (r0+r1)+(r2+r3)
            s = s + __shfl_xor(s, 32, 64);       // h=0: full np pairwise tree
            xs = __shfl(s, lo4, 64);             // broadcast h=0 lane's value
        }

        // ---- token B-frags resident (8 regs) ----
        half8 bh0 = ((const half8*)xAh)[(wave * 2 + 0) * 64 + lane];
        half8 bh1 = ((const half8*)xAh)[(wave * 2 + 1) * 64 + lane];

        // ---- main: 32 code-blocks; approx score drops xs (const per token:
        //      gap m2-m1 invariant; err fp16+reassoc << EPS/2) ----
        float m1 = FLT_MAX, m2 = FLT_MAX;
        int   k1 = 0x7FFFFFFF;
        #pragma unroll 8
        for (int blk = 0; blk < 32; ++blk) {
            half8 ah0 = ((const half8*)eF)[(blk * 2 + 0) * 64 + lane];
            half8 ah1 = ((const half8*)eF)[(blk * 2 + 1) * 64 + lane];
            f32x4 c = {0.f, 0.f, 0.f, 0.f};
            c = __builtin_amdgcn_mfma_f32_16x16x32_f16(ah0, bh0, c, 0, 0, 0);
            c = __builtin_amdgcn_mfma_f32_16x16x32_f16(ah1, bh1, c, 0, 0, 0);
            float4 es4 = *reinterpret_cast<const float4*>(&esq_s[blk * 16 + hi4 * 4]);
            float es[4] = {es4.x, es4.y, es4.z, es4.w};
            #pragma unroll
            for (int r = 0; r < 4; ++r) {
                float sc = fmaf(-2.0f, c[r], es[r]);   // shifted score
                int   cd = blk * 16 + hi4 * 4 + r;     // ascending within lane
                if (sc < m1)      { m2 = m1; m1 = sc; k1 = cd; }
                else              { m2 = fminf(m2, sc); }
            }
        }

        // ---- merge 4 lanes per token (xor 16, 32) — r9-validated logic ----
        #pragma unroll
        for (int off = 16; off < 64; off <<= 1) {
            float ov = __shfl_xor(m1, off, 64);
            int   ok = __shfl_xor(k1, off, 64);
            float o2 = __shfl_xor(m2, off, 64);
            float n2 = fminf(fminf(m2, o2), fmaxf(m1, ov));
            if (ov < m1 || (ov == m1 && ok < k1)) { m1 = ov; k1 = ok; }
            m2 = n2;
        }

        // ---- decide / flag (lanes 0..15 own tokens wave*16+lane) ----
        bool mine = (lane < 16);
        bool flg  = mine && (m2 <= m1 + EPS);
        if (mine && !flg) bestk_s[wave * 16 + lane] = k1;
        unsigned long long bal = __ballot(flg);

        // ---- exact pass: wave-local, per flagged token; np-bitexact chain --
        while (bal) {
            int tk_local = (int)__builtin_ctzll(bal);
            bal &= bal - 1;
            int token = wave * 16 + tk_local;
            float xs_e = __shfl(xs, tk_local, 64);
            float d0 = 0.f, d1 = 0.f, d2 = 0.f, d3 = 0.f;
            float d4 = 0.f, d5 = 0.f, d6 = 0.f, d7 = 0.f;
            const float* Ep = E + 8 * lane;
            #pragma unroll 4
            for (int d = 0; d < 64; ++d) {
                float xv = xT[d][token];         // wave-uniform broadcast
                float4 e0 = *reinterpret_cast<const float4*>(Ep + d * K_);
                float4 e1 = *reinterpret_cast<const float4*>(Ep + d * K_ + 4);
                d0 = fmaf(xv, e0.x, d0); d1 = fmaf(xv, e0.y, d1);
                d2 = fmaf(xv, e0.z, d2); d3 = fmaf(xv, e0.w, d3);
                d4 = fmaf(xv, e1.x, d4); d5 = fmaf(xv, e1.y, d5);
                d6 = fmaf(xv, e1.z, d6); d7 = fmaf(xv, e1.w, d7);
            }
            float4 qa = *reinterpret_cast<const float4*>(&esq_s[8 * lane]);
            float4 qb = *reinterpret_cast<const float4*>(&esq_s[8 * lane + 4]);
            float sc[8];
            sc[0] = (xs_e - 2.0f * d0) + qa.x; sc[1] = (xs_e - 2.0f * d1) + qa.y;
            sc[2] = (xs_e - 2.0f * d2) + qa.z; sc[3] = (xs_e - 2.0f * d3) + qa.w;
            sc[4] = (xs_e - 2.0f * d4) + qb.x; sc[5] = (xs_e - 2.0f * d5) + qb.y;
            sc[6] = (xs_e - 2.0f * d6) + qb.z; sc[7] = (xs_e - 2.0f * d7) + qb.w;
            unsigned long long pk = ~0ULL;
            #pragma unroll
            for (int j = 0; j < 8; ++j) {        // ascending code: first-min kept
                unsigned long long p =
                    ((unsigned long long)f32_sortable(sc[j]) << 32) |
                    (unsigned)(8 * lane + j);
                if (p < pk) pk = p;
            }
            #pragma unroll
            for (int off = 1; off < 64; off <<= 1) {
                unsigned long long o = __shfl_xor(pk, off, 64);
                if (o < pk) pk = o;
            }
            if (lane == 0)
                bestk_s[token] = (int)(unsigned)(pk & 0xFFFFFFFFULL);
        }
        __syncthreads();                                         // B3

        // ---- epilogue: gather exact fp32 rows, float4 stores, 128 tokens --
        {
            int d  = tid >> 3;                   // 0..63
            int q8 = tid & 7;
            #pragma unroll
            for (int it = 0; it < 4; ++it) {
                int quad = q8 + it * 8;          // 0..31
                int i4 = quad * 4;
                int k0 = bestk_s[i4],     kk1 = bestk_s[i4 + 1];
                int k2 = bestk_s[i4 + 2], k3  = bestk_s[i4 + 3];
                float4 v;
                v.x = E[d * K_ + k0];  v.y = E[d * K_ + kk1];
                v.z = E[d * K_ + k2];  v.w = E[d * K_ + k3];
                *reinterpret_cast<float4*>(out_emb + ((size_t)(b * 64 + d)) * L_ + l0 + i4) = v;
            }
        }
        if (tid < TILE_TOK)
            out_idx[(size_t)b * L_ + l0 + tid] = (float)bestk_s[tid];
    }
}

extern "C" void kernel_launch(void* const* d_in, const int* in_sizes, int n_in,
                              void* d_out, int out_size, void* d_ws, size_t ws_size,
                              hipStream_t stream) {
    const float* X = (const float*)d_in[0];   // (B, D, L) fp32
    const float* E = (const float*)d_in[1];   // (D, K) fp32
    float* out     = (float*)d_out;
    float* out_emb = out;
    float* out_idx = out + (size_t)B_ * D_ * L_;
    vq_mfma_kernel<<<NBLOCKS, 512, 0, stream>>>(X, E, out_emb, out_idx);
}